// Round 16
// baseline (333.731 us; speedup 1.0000x reference)
//
#include <hip/hip_runtime.h>

// Problem constants
//  N=8, C=512, P=64, G=8, S_D=512, H=W=128, HW=16384
//  style: [8,512,32,32]  predicted: [8,512,128,128]
//
// ROUND 16: r13 champion byte-for-byte, with k_conv launched 3x (idempotent)
// to MEASURE conv's duration: conv_dur = (total - 167.9us)/2.

typedef __attribute__((ext_vector_type(8))) short bf16x8;
typedef __attribute__((ext_vector_type(4))) float f32x4;

__device__ __forceinline__ float lrelu(float v) { return v > 0.f ? v : 0.01f * v; }

__device__ __forceinline__ unsigned short f2bf(float f) {
    unsigned int u = __float_as_uint(f);
    unsigned int r = (u + 0x7FFFu + ((u >> 16) & 1u)) >> 16;   // round-nearest-even
    return (unsigned short)r;
}

// ---------- K1: adaptive avg pool of style -> s[8*512]; wave per channel ----------
__global__ void k_pool(const float* __restrict__ style, float* __restrict__ s) {
    int wv = threadIdx.x >> 6, lane = threadIdx.x & 63;
    int b = blockIdx.x * 4 + wv;              // n*512 + c, 0..4095
    const float4* p4 = (const float4*)(style + (size_t)b * 1024);
    float v = 0.f;
    #pragma unroll
    for (int i = 0; i < 4; ++i) {
        float4 t = p4[lane + 64 * i];
        v += t.x + t.y + t.z + t.w;
    }
    #pragma unroll
    for (int off = 32; off > 0; off >>= 1) v += __shfl_xor(v, off, 64);
    if (lane == 0) s[b] = v * (1.f / 1024.f);
}

// ---------- K2: hk = lrelu(s@W1^T+b1), hb = lrelu(s@Wb1^T+bb1) ----------
__global__ void k_mlp1(const float* __restrict__ s, const float* __restrict__ W1,
                       const float* __restrict__ b1, const float* __restrict__ Wb1,
                       const float* __restrict__ bb1, float* __restrict__ hk,
                       float* __restrict__ hb) {
    __shared__ float sv[4096];                // s[8][512]
    const float4* s4 = (const float4*)s;
    float4* sv4 = (float4*)sv;
    #pragma unroll
    for (int i = 0; i < 4; ++i) sv4[threadIdx.x + 256 * i] = s4[threadIdx.x + 256 * i];
    __syncthreads();
    int wv = threadIdx.x >> 6, lane = threadIdx.x & 63;
    int row = blockIdx.x * 4 + wv;            // 0..1023
    int r2 = row & 511;
    const float* wrow = (row < 512) ? W1 + (size_t)r2 * 512 : Wb1 + (size_t)r2 * 512;
    float bias = (row < 512) ? b1[r2] : bb1[r2];
    float acc[8] = {0.f,0.f,0.f,0.f,0.f,0.f,0.f,0.f};
    #pragma unroll
    for (int c = 0; c < 2; ++c) {
        float4 w4 = *(const float4*)(wrow + lane * 4 + 256 * c);
        #pragma unroll
        for (int n = 0; n < 8; ++n) {
            float4 h4 = *(const float4*)(sv + n * 512 + lane * 4 + 256 * c);
            acc[n] += w4.x * h4.x + w4.y * h4.y + w4.z * h4.z + w4.w * h4.w;
        }
    }
    #pragma unroll
    for (int n = 0; n < 8; ++n) {
        float v = acc[n];
        #pragma unroll
        for (int off = 32; off > 0; off >>= 1) v += __shfl_xor(v, off, 64);
        acc[n] = v;
    }
    if (lane == 0) {
        float* dst = (row < 512) ? hk : hb;
        #pragma unroll
        for (int n = 0; n < 8; ++n) dst[n * 512 + r2] = lrelu(acc[n] + bias);
    }
}

// ---------- K3: merged {mlp2} + {instance-norm stats} by block range ----------
__global__ void k_mlp2stats(const float* __restrict__ hk, const float* __restrict__ hb,
                            const float* __restrict__ W2, const float* __restrict__ b2,
                            const float* __restrict__ Wb2, const float* __restrict__ bb2,
                            const float* __restrict__ x,
                            float* __restrict__ kn, float* __restrict__ bvec,
                            float* __restrict__ mu, float* __restrict__ rs) {
    __shared__ float h[8192];
    __shared__ float ps[4], pq[4];
    int tid = threadIdx.x, wv = tid >> 6, lane = tid & 63;
    if (blockIdx.x < 8320) {
        const float4* hk4 = (const float4*)hk;
        const float4* hb4 = (const float4*)hb;
        float4* h4 = (float4*)h;
        #pragma unroll
        for (int i = 0; i < 4; ++i) {
            h4[tid + 256 * i]        = hk4[tid + 256 * i];
            h4[1024 + tid + 256 * i] = hb4[tid + 256 * i];
        }
        __syncthreads();
        int row = blockIdx.x * 4 + wv;        // 0..33279
        const float* wrow;
        const float* hbase;
        float bias;
        int r2 = row - 32768;
        if (row < 32768) { wrow = W2 + (size_t)row * 512; hbase = h; bias = b2[row]; }
        else             { wrow = Wb2 + (size_t)r2 * 512; hbase = h + 4096; bias = bb2[r2]; }
        float acc[8] = {0.f,0.f,0.f,0.f,0.f,0.f,0.f,0.f};
        #pragma unroll
        for (int c = 0; c < 2; ++c) {
            f32x4 w4 = __builtin_nontemporal_load((const f32x4*)(wrow + lane * 4 + 256 * c));
            #pragma unroll
            for (int n = 0; n < 8; ++n) {
                float4 x4 = *(const float4*)(hbase + n * 512 + lane * 4 + 256 * c);
                acc[n] += w4[0] * x4.x + w4[1] * x4.y + w4[2] * x4.z + w4[3] * x4.w;
            }
        }
        #pragma unroll
        for (int n = 0; n < 8; ++n) {
            float v = acc[n];
            #pragma unroll
            for (int off = 32; off > 0; off >>= 1) v += __shfl_xor(v, off, 64);
            acc[n] = v;
        }
        if (lane == 0) {
            if (row < 32768) {
                #pragma unroll
                for (int n = 0; n < 8; ++n) kn[(size_t)n * 32768 + row] = acc[n] + bias;
            } else {
                #pragma unroll
                for (int n = 0; n < 8; ++n) bvec[n * 512 + r2] = acc[n] + bias;
            }
        }
    } else {
        int b = blockIdx.x - 8320;            // n*512 + c
        const float4* p4 = (const float4*)(x + (size_t)b * 16384);
        float sm = 0.f, q = 0.f;
        #pragma unroll
        for (int i = 0; i < 16; ++i) {
            float4 v = p4[tid + 256 * i];
            sm += v.x + v.y + v.z + v.w;
            q += v.x * v.x + v.y * v.y + v.z * v.z + v.w * v.w;
        }
        #pragma unroll
        for (int off = 32; off > 0; off >>= 1) {
            sm += __shfl_xor(sm, off, 64);
            q  += __shfl_xor(q, off, 64);
        }
        if (lane == 0) { ps[wv] = sm; pq[wv] = q; }
        __syncthreads();
        if (tid == 0) {
            float S = ps[0] + ps[1] + ps[2] + ps[3];
            float Q = pq[0] + pq[1] + pq[2] + pq[3];
            float m = S * (1.f / 16384.f);
            float v = Q * (1.f / 16384.f) - m * m;
            mu[b] = m;
            rs[b] = rsqrtf(v + 1e-5f);
        }
    }
}

// ---------- K4: fold norm into kernel; emit bf16 K' [o][p] + fused bias bp ----------
__global__ void k_fold(const float* __restrict__ kn, const float* __restrict__ bvec,
                       const float* __restrict__ mu, const float* __restrict__ rs,
                       unsigned short* __restrict__ Kp, float* __restrict__ bp) {
    int wv = threadIdx.x >> 6, lane = threadIdx.x & 63;
    int t = blockIdx.x * 4 + wv;              // 0..4095 = n*512 + g*64 + o
    int n = t >> 9, rem = t & 511, g = rem >> 6;
    int ci = n * 512 + g * 64 + lane;
    float kv = kn[(size_t)n * 32768 + (size_t)rem * 64 + lane] * rs[ci];
    Kp[(size_t)t * 64 + lane] = f2bf(kv);
    float pm = kv * mu[ci];
    #pragma unroll
    for (int off = 32; off > 0; off >>= 1) pm += __shfl_xor(pm, off, 64);
    if (lane == 0) bp[t] = bvec[n * 512 + rem] - pm;
}

// ---------- K5: MFMA grouped conv with LDS store-bounce (r13 exact) ----------
__global__ __launch_bounds__(256) void k_conv(const float* __restrict__ x,
                                              const unsigned short* __restrict__ Kp,
                                              const float* __restrict__ bp,
                                              float* __restrict__ out) {
    __shared__ float obuf[4][64 * 36];        // per-wave 9 KB bounce, rows padded to 36
    int bid = 4095 - (int)blockIdx.x;         // reverse traversal (L3 LRU-friendly)
    int ng = bid >> 6, slab = bid & 63;
    int wv = threadIdx.x >> 6, lane = threadIdx.x & 63;
    int l15 = lane & 15, lg = lane >> 4;
    int l8 = lane & 7, lo = lane >> 3;

    const unsigned short* kpb = Kp + (size_t)ng * 4096;
    bf16x8 kfr[4][2];
    #pragma unroll
    for (int ob = 0; ob < 4; ++ob)
        #pragma unroll
        for (int kk = 0; kk < 2; ++kk)
            kfr[ob][kk] = *(const bf16x8*)(kpb + (ob * 16 + l15) * 64 + kk * 32 + lg * 8);

    float bias[4];
    #pragma unroll
    for (int ob = 0; ob < 4; ++ob)
        bias[ob] = bp[ng * 64 + ob * 16 + l15];

    const size_t xbase = (size_t)ng * 64 * 16384;   // channel p at xbase + p*16384
    int px0 = slab * 256 + wv * 64;
    float* obw = obuf[wv];

    #pragma unroll
    for (int cp = 0; cp < 2; ++cp) {
        #pragma unroll
        for (int c = 0; c < 2; ++c) {
            int pxb = px0 + cp * 32 + c * 16;
            bf16x8 afr[2];
            #pragma unroll
            for (int kk = 0; kk < 2; ++kk)
                #pragma unroll
                for (int j = 0; j < 8; ++j) {
                    int p = kk * 32 + lg * 8 + j;
                    afr[kk][j] = (short)f2bf(x[xbase + (size_t)p * 16384 + pxb + l15]);
                }
            #pragma unroll
            for (int ob = 0; ob < 4; ++ob) {
                f32x4 acc = { bias[ob], bias[ob], bias[ob], bias[ob] };
                acc = __builtin_amdgcn_mfma_f32_16x16x32_bf16(afr[0], kfr[ob][0], acc, 0, 0, 0);
                acc = __builtin_amdgcn_mfma_f32_16x16x32_bf16(afr[1], kfr[ob][1], acc, 0, 0, 0);
                *(f32x4*)(obw + (ob * 16 + l15) * 36 + c * 16 + lg * 4) = acc;
            }
        }
        #pragma unroll
        for (int i = 0; i < 8; ++i) {
            int o = i * 8 + lo;
            f32x4 v = *(const f32x4*)(obw + o * 36 + l8 * 4);
            f32x4* dst = (f32x4*)(out + (size_t)(ng * 64 + o) * 16384 + px0 + cp * 32 + l8 * 4);
            __builtin_nontemporal_store(v, dst);
        }
    }
}

extern "C" void kernel_launch(void* const* d_in, const int* in_sizes, int n_in,
                              void* d_out, int out_size, void* d_ws, size_t ws_size,
                              hipStream_t stream) {
    const float* style = (const float*)d_in[0];
    const float* pred  = (const float*)d_in[1];
    const float* W1    = (const float*)d_in[2];
    const float* b1    = (const float*)d_in[3];
    const float* W2    = (const float*)d_in[4];
    const float* b2    = (const float*)d_in[5];
    const float* Wb1   = (const float*)d_in[6];
    const float* bb1   = (const float*)d_in[7];
    const float* Wb2   = (const float*)d_in[8];
    const float* bb2   = (const float*)d_in[9];
    float* out = (float*)d_out;

    // workspace layout (floats; all offsets 16B-aligned)
    float* ws   = (float*)d_ws;
    float* s    = ws;                 // 4096
    float* hk   = s + 4096;           // 4096
    float* hb   = hk + 4096;          // 4096
    float* kn   = hb + 4096;          // 262144
    float* bvec = kn + 262144;        // 4096
    float* mu   = bvec + 4096;        // 4096
    float* rs   = mu + 4096;          // 4096
    float* bp   = rs + 4096;          // 4096
    unsigned short* Kp = (unsigned short*)(bp + 4096);  // 262144 ushorts

    k_pool     <<<1024,  256, 0, stream>>>(style, s);
    k_mlp1     <<<256,   256, 0, stream>>>(s, W1, b1, Wb1, bb1, hk, hb);
    k_mlp2stats<<<12416, 256, 0, stream>>>(hk, hb, W2, b2, Wb2, bb2, pred, kn, bvec, mu, rs);
    k_fold     <<<1024,  256, 0, stream>>>(kn, bvec, mu, rs, Kp, bp);
    // MEASUREMENT: conv launched 3x (idempotent rewrite of out).
    // conv_dur = (total_us - 167.9) / 2
    k_conv     <<<4096,  256, 0, stream>>>(pred, Kp, bp, out);
    k_conv     <<<4096,  256, 0, stream>>>(pred, Kp, bp, out);
    k_conv     <<<4096,  256, 0, stream>>>(pred, Kp, bp, out);
}

// Round 17
// 159.794 us; speedup vs baseline: 2.0885x; 2.0885x over previous
//
#include <hip/hip_runtime.h>

// Problem constants
//  N=8, C=512, P=64, G=8, S_D=512, H=W=128, HW=16384
//  style: [8,512,32,32]  predicted: [8,512,128,128]

typedef __attribute__((ext_vector_type(8))) short bf16x8;
typedef __attribute__((ext_vector_type(4))) float f32x4;

__device__ __forceinline__ float lrelu(float v) { return v > 0.f ? v : 0.01f * v; }

__device__ __forceinline__ unsigned short f2bf(float f) {
    unsigned int u = __float_as_uint(f);
    unsigned int r = (u + 0x7FFFu + ((u >> 16) & 1u)) >> 16;   // round-nearest-even
    return (unsigned short)r;
}

// ---------- K1: adaptive avg pool of style -> s[8*512]; wave per channel ----------
__global__ void k_pool(const float* __restrict__ style, float* __restrict__ s) {
    int wv = threadIdx.x >> 6, lane = threadIdx.x & 63;
    int b = blockIdx.x * 4 + wv;              // n*512 + c, 0..4095
    const float4* p4 = (const float4*)(style + (size_t)b * 1024);
    float v = 0.f;
    #pragma unroll
    for (int i = 0; i < 4; ++i) {
        float4 t = p4[lane + 64 * i];
        v += t.x + t.y + t.z + t.w;
    }
    #pragma unroll
    for (int off = 32; off > 0; off >>= 1) v += __shfl_xor(v, off, 64);
    if (lane == 0) s[b] = v * (1.f / 1024.f);
}

// ---------- K2: hk = lrelu(s@W1^T+b1), hb = lrelu(s@Wb1^T+bb1) ----------
__global__ void k_mlp1(const float* __restrict__ s, const float* __restrict__ W1,
                       const float* __restrict__ b1, const float* __restrict__ Wb1,
                       const float* __restrict__ bb1, float* __restrict__ hk,
                       float* __restrict__ hb) {
    __shared__ float sv[4096];                // s[8][512]
    const float4* s4 = (const float4*)s;
    float4* sv4 = (float4*)sv;
    #pragma unroll
    for (int i = 0; i < 4; ++i) sv4[threadIdx.x + 256 * i] = s4[threadIdx.x + 256 * i];
    __syncthreads();
    int wv = threadIdx.x >> 6, lane = threadIdx.x & 63;
    int row = blockIdx.x * 4 + wv;            // 0..1023
    int r2 = row & 511;
    const float* wrow = (row < 512) ? W1 + (size_t)r2 * 512 : Wb1 + (size_t)r2 * 512;
    float bias = (row < 512) ? b1[r2] : bb1[r2];
    float acc[8] = {0.f,0.f,0.f,0.f,0.f,0.f,0.f,0.f};
    #pragma unroll
    for (int c = 0; c < 2; ++c) {
        float4 w4 = *(const float4*)(wrow + lane * 4 + 256 * c);
        #pragma unroll
        for (int n = 0; n < 8; ++n) {
            float4 h4 = *(const float4*)(sv + n * 512 + lane * 4 + 256 * c);
            acc[n] += w4.x * h4.x + w4.y * h4.y + w4.z * h4.z + w4.w * h4.w;
        }
    }
    #pragma unroll
    for (int n = 0; n < 8; ++n) {
        float v = acc[n];
        #pragma unroll
        for (int off = 32; off > 0; off >>= 1) v += __shfl_xor(v, off, 64);
        acc[n] = v;
    }
    if (lane == 0) {
        float* dst = (row < 512) ? hk : hb;
        #pragma unroll
        for (int n = 0; n < 8; ++n) dst[n * 512 + r2] = lrelu(acc[n] + bias);
    }
}

// ---------- K3: merged {mlp2, row-batched 16/block} + {stats} by block range ----------
// blocks 0..2079: mlp2 -- each block stages hk/hb ONCE and computes 16 rows
// (wave w does rows base+w*4 .. +3, unrolled -> 4 independent dots in flight).
// Restage traffic: 2080 x 32 KB = 66 MB (was 266 MB at 4 rows/block).
// blocks 2080..6175: stats (block per pred channel) -> mu, rs.
__global__ void k_mlp2stats(const float* __restrict__ hk, const float* __restrict__ hb,
                            const float* __restrict__ W2, const float* __restrict__ b2,
                            const float* __restrict__ Wb2, const float* __restrict__ bb2,
                            const float* __restrict__ x,
                            float* __restrict__ kn, float* __restrict__ bvec,
                            float* __restrict__ mu, float* __restrict__ rs) {
    __shared__ float h[8192];
    __shared__ float ps[4], pq[4];
    int tid = threadIdx.x, wv = tid >> 6, lane = tid & 63;
    if (blockIdx.x < 2080) {
        const float4* hk4 = (const float4*)hk;
        const float4* hb4 = (const float4*)hb;
        float4* h4 = (float4*)h;
        #pragma unroll
        for (int i = 0; i < 4; ++i) {
            h4[tid + 256 * i]        = hk4[tid + 256 * i];
            h4[1024 + tid + 256 * i] = hb4[tid + 256 * i];
        }
        __syncthreads();
        int base = blockIdx.x * 16 + wv * 4;  // first of this wave's 4 rows
        #pragma unroll
        for (int rr = 0; rr < 4; ++rr) {
            int row = base + rr;              // 0..33279
            const float* wrow;
            const float* hbase;
            float bias;
            int r2 = row - 32768;
            if (row < 32768) { wrow = W2 + (size_t)row * 512; hbase = h; bias = b2[row]; }
            else             { wrow = Wb2 + (size_t)r2 * 512; hbase = h + 4096; bias = bb2[r2]; }
            float acc[8] = {0.f,0.f,0.f,0.f,0.f,0.f,0.f,0.f};
            #pragma unroll
            for (int c = 0; c < 2; ++c) {
                f32x4 w4 = __builtin_nontemporal_load((const f32x4*)(wrow + lane * 4 + 256 * c));
                #pragma unroll
                for (int n = 0; n < 8; ++n) {
                    float4 x4 = *(const float4*)(hbase + n * 512 + lane * 4 + 256 * c);
                    acc[n] += w4[0] * x4.x + w4[1] * x4.y + w4[2] * x4.z + w4[3] * x4.w;
                }
            }
            #pragma unroll
            for (int n = 0; n < 8; ++n) {
                float v = acc[n];
                #pragma unroll
                for (int off = 32; off > 0; off >>= 1) v += __shfl_xor(v, off, 64);
                acc[n] = v;
            }
            if (lane == 0) {
                if (row < 32768) {
                    #pragma unroll
                    for (int n = 0; n < 8; ++n) kn[(size_t)n * 32768 + row] = acc[n] + bias;
                } else {
                    #pragma unroll
                    for (int n = 0; n < 8; ++n) bvec[n * 512 + r2] = acc[n] + bias;
                }
            }
        }
    } else {
        int b = blockIdx.x - 2080;            // n*512 + c
        const float4* p4 = (const float4*)(x + (size_t)b * 16384);
        float sm = 0.f, q = 0.f;
        #pragma unroll
        for (int i = 0; i < 16; ++i) {
            float4 v = p4[tid + 256 * i];
            sm += v.x + v.y + v.z + v.w;
            q += v.x * v.x + v.y * v.y + v.z * v.z + v.w * v.w;
        }
        #pragma unroll
        for (int off = 32; off > 0; off >>= 1) {
            sm += __shfl_xor(sm, off, 64);
            q  += __shfl_xor(q, off, 64);
        }
        if (lane == 0) { ps[wv] = sm; pq[wv] = q; }
        __syncthreads();
        if (tid == 0) {
            float S = ps[0] + ps[1] + ps[2] + ps[3];
            float Q = pq[0] + pq[1] + pq[2] + pq[3];
            float m = S * (1.f / 16384.f);
            float v = Q * (1.f / 16384.f) - m * m;
            mu[b] = m;
            rs[b] = rsqrtf(v + 1e-5f);
        }
    }
}

// ---------- K4: fold norm into kernel; emit bf16 K' [o][p] + fused bias bp ----------
__global__ void k_fold(const float* __restrict__ kn, const float* __restrict__ bvec,
                       const float* __restrict__ mu, const float* __restrict__ rs,
                       unsigned short* __restrict__ Kp, float* __restrict__ bp) {
    int wv = threadIdx.x >> 6, lane = threadIdx.x & 63;
    int t = blockIdx.x * 4 + wv;              // 0..4095 = n*512 + g*64 + o
    int n = t >> 9, rem = t & 511, g = rem >> 6;
    int ci = n * 512 + g * 64 + lane;
    float kv = kn[(size_t)n * 32768 + (size_t)rem * 64 + lane] * rs[ci];
    Kp[(size_t)t * 64 + lane] = f2bf(kv);
    float pm = kv * mu[ci];
    #pragma unroll
    for (int off = 32; off > 0; off >>= 1) pm += __shfl_xor(pm, off, 64);
    if (lane == 0) bp[t] = bvec[n * 512 + rem] - pm;
}

// ---------- K5: MFMA grouped conv with LDS store-bounce (r13 exact) ----------
__global__ __launch_bounds__(256) void k_conv(const float* __restrict__ x,
                                              const unsigned short* __restrict__ Kp,
                                              const float* __restrict__ bp,
                                              float* __restrict__ out) {
    __shared__ float obuf[4][64 * 36];        // per-wave 9 KB bounce, rows padded to 36
    int bid = 4095 - (int)blockIdx.x;         // reverse traversal (L3 LRU-friendly)
    int ng = bid >> 6, slab = bid & 63;
    int wv = threadIdx.x >> 6, lane = threadIdx.x & 63;
    int l15 = lane & 15, lg = lane >> 4;
    int l8 = lane & 7, lo = lane >> 3;

    const unsigned short* kpb = Kp + (size_t)ng * 4096;
    bf16x8 kfr[4][2];
    #pragma unroll
    for (int ob = 0; ob < 4; ++ob)
        #pragma unroll
        for (int kk = 0; kk < 2; ++kk)
            kfr[ob][kk] = *(const bf16x8*)(kpb + (ob * 16 + l15) * 64 + kk * 32 + lg * 8);

    float bias[4];
    #pragma unroll
    for (int ob = 0; ob < 4; ++ob)
        bias[ob] = bp[ng * 64 + ob * 16 + l15];

    const size_t xbase = (size_t)ng * 64 * 16384;   // channel p at xbase + p*16384
    int px0 = slab * 256 + wv * 64;
    float* obw = obuf[wv];

    #pragma unroll
    for (int cp = 0; cp < 2; ++cp) {
        #pragma unroll
        for (int c = 0; c < 2; ++c) {
            int pxb = px0 + cp * 32 + c * 16;
            bf16x8 afr[2];
            #pragma unroll
            for (int kk = 0; kk < 2; ++kk)
                #pragma unroll
                for (int j = 0; j < 8; ++j) {
                    int p = kk * 32 + lg * 8 + j;
                    afr[kk][j] = (short)f2bf(x[xbase + (size_t)p * 16384 + pxb + l15]);
                }
            #pragma unroll
            for (int ob = 0; ob < 4; ++ob) {
                f32x4 acc = { bias[ob], bias[ob], bias[ob], bias[ob] };
                acc = __builtin_amdgcn_mfma_f32_16x16x32_bf16(afr[0], kfr[ob][0], acc, 0, 0, 0);
                acc = __builtin_amdgcn_mfma_f32_16x16x32_bf16(afr[1], kfr[ob][1], acc, 0, 0, 0);
                *(f32x4*)(obw + (ob * 16 + l15) * 36 + c * 16 + lg * 4) = acc;
            }
        }
        #pragma unroll
        for (int i = 0; i < 8; ++i) {
            int o = i * 8 + lo;
            f32x4 v = *(const f32x4*)(obw + o * 36 + l8 * 4);
            f32x4* dst = (f32x4*)(out + (size_t)(ng * 64 + o) * 16384 + px0 + cp * 32 + l8 * 4);
            __builtin_nontemporal_store(v, dst);
        }
    }
}

extern "C" void kernel_launch(void* const* d_in, const int* in_sizes, int n_in,
                              void* d_out, int out_size, void* d_ws, size_t ws_size,
                              hipStream_t stream) {
    const float* style = (const float*)d_in[0];
    const float* pred  = (const float*)d_in[1];
    const float* W1    = (const float*)d_in[2];
    const float* b1    = (const float*)d_in[3];
    const float* W2    = (const float*)d_in[4];
    const float* b2    = (const float*)d_in[5];
    const float* Wb1   = (const float*)d_in[6];
    const float* bb1   = (const float*)d_in[7];
    const float* Wb2   = (const float*)d_in[8];
    const float* bb2   = (const float*)d_in[9];
    float* out = (float*)d_out;

    // workspace layout (floats; all offsets 16B-aligned)
    float* ws   = (float*)d_ws;
    float* s    = ws;                 // 4096
    float* hk   = s + 4096;           // 4096
    float* hb   = hk + 4096;          // 4096
    float* kn   = hb + 4096;          // 262144
    float* bvec = kn + 262144;        // 4096
    float* mu   = bvec + 4096;        // 4096
    float* rs   = mu + 4096;          // 4096
    float* bp   = rs + 4096;          // 4096
    unsigned short* Kp = (unsigned short*)(bp + 4096);  // 262144 ushorts

    k_pool     <<<1024, 256, 0, stream>>>(style, s);
    k_mlp1     <<<256,  256, 0, stream>>>(s, W1, b1, Wb1, bb1, hk, hb);
    k_mlp2stats<<<6176, 256, 0, stream>>>(hk, hb, W2, b2, Wb2, bb2, pred, kn, bvec, mu, rs);
    k_fold     <<<1024, 256, 0, stream>>>(kn, bvec, mu, rs, Kp, bp);
    k_conv     <<<4096, 256, 0, stream>>>(pred, Kp, bp, out);
}